// Round 8
// baseline (12256.228 us; speedup 1.0000x reference)
//
#include <hip/hip_runtime.h>
#include <hip/hip_fp16.h>
#include <cstdint>

#define B_SZ 4
#define T_SZ 512
#define D_SZ 768
#define H_SZ 768
#define G4   3072           // 4*H
#define V_SZ 50257
#define V_PAD 50304         // 393*128
#define M_SZ 2048           // T*B
#define FUSE_WGS 96         // one block = 8 cols of L0 (waves 0-3) + 8 cols of L1 (waves 4-7)

using half8 = __attribute__((ext_vector_type(8))) _Float16;
using f32x4 = __attribute__((ext_vector_type(4))) float;
typedef unsigned long long ull;

// ---------------- conversion kernels ----------------

__global__ void conv_A0(const float* __restrict__ reps, _Float16* __restrict__ A0) {
  // A0[(t*4+b)*768 + k] = reps[(b*512 + t)*768 + k]
  int idx = blockIdx.x * blockDim.x + threadIdx.x;
  const int total = M_SZ * D_SZ;
  for (; idx < total; idx += gridDim.x * blockDim.x) {
    int k = idx % D_SZ, m = idx / D_SZ;
    int t = m >> 2, b = m & 3;
    A0[idx] = (_Float16)reps[(b * T_SZ + t) * D_SZ + k];
  }
}

__global__ void conv_cast(const float* __restrict__ src, _Float16* __restrict__ dst, int n) {
  int idx = blockIdx.x * blockDim.x + threadIdx.x;
  for (; idx < n; idx += gridDim.x * blockDim.x) dst[idx] = (_Float16)src[idx];
}

__global__ void conv_head(const float* __restrict__ w, _Float16* __restrict__ dst) {
  int idx = blockIdx.x * blockDim.x + threadIdx.x;
  const int total = V_PAD * H_SZ;
  for (; idx < total; idx += gridDim.x * blockDim.x) {
    int n = idx / H_SZ, k = idx % H_SZ;
    dst[idx] = (n < V_SZ) ? (_Float16)w[n * H_SZ + k] : (_Float16)0.f;
  }
}

// ---------------- f16 MFMA GEMM: C[m][n] = sum_k A[m][k]*B[n][k] + bias[n] ----------------

__global__ __launch_bounds__(256) void gemm_bt_f16(
    const _Float16* __restrict__ A, const _Float16* __restrict__ B,
    const float* __restrict__ bias, float* __restrict__ C,
    int M, int N, int K, int mode, int Nreal)
{
  __shared__ __align__(16) _Float16 As[128][32];
  __shared__ __align__(16) _Float16 Bs[128][32];
  const int t = threadIdx.x;
  const int lane = t & 63, w = t >> 6;
  const int wr = w >> 1, wc = w & 1;
  const int m0 = blockIdx.x * 128, n0 = blockIdx.y * 128;

  f32x4 acc[4][4] = {};

  const int srow = t >> 2;
  const int scol = (t & 3) * 8;

  for (int k0 = 0; k0 < K; k0 += 32) {
    uint4 av0 = *(const uint4*)&A[(size_t)(m0 + srow) * K + k0 + scol];
    uint4 av1 = *(const uint4*)&A[(size_t)(m0 + 64 + srow) * K + k0 + scol];
    uint4 bv0 = *(const uint4*)&B[(size_t)(n0 + srow) * K + k0 + scol];
    uint4 bv1 = *(const uint4*)&B[(size_t)(n0 + 64 + srow) * K + k0 + scol];
    __syncthreads();
    *(uint4*)&As[srow][scol]      = av0;
    *(uint4*)&As[64 + srow][scol] = av1;
    *(uint4*)&Bs[srow][scol]      = bv0;
    *(uint4*)&Bs[64 + srow][scol] = bv1;
    __syncthreads();

    const int fr = lane & 15, k8 = (lane >> 4) * 8;
    half8 af[4], bf[4];
#pragma unroll
    for (int i = 0; i < 4; ++i) {
      af[i] = *(const half8*)&As[wr * 64 + i * 16 + fr][k8];
      bf[i] = *(const half8*)&Bs[wc * 64 + i * 16 + fr][k8];
    }
#pragma unroll
    for (int i = 0; i < 4; ++i)
#pragma unroll
      for (int j = 0; j < 4; ++j)
        acc[i][j] = __builtin_amdgcn_mfma_f32_16x16x32_f16(af[i], bf[j], acc[i][j], 0, 0, 0);
  }

  const int fr = lane & 15, rq = lane >> 4;
#pragma unroll
  for (int i = 0; i < 4; ++i) {
#pragma unroll
    for (int j = 0; j < 4; ++j) {
      int n = n0 + wc * 64 + j * 16 + fr;
      if (n >= Nreal) continue;
      float bv = bias[n];
#pragma unroll
      for (int r = 0; r < 4; ++r) {
        int m = m0 + wr * 64 + i * 16 + rq * 4 + r;
        float v = acc[i][j][r] + bv;
        if (mode == 0) {
          C[(size_t)m * N + n] = v;
        } else {
          int tt = m >> 2, bb = m & 3;
          C[(size_t)(bb * T_SZ + tt) * V_SZ + n] = v;
        }
      }
    }
  }
}

// ---------------- fused 2-layer pipelined LSTM scan: 96 blocks x 512 threads ----------------
// Block owns h-cols [j0, j0+8) of BOTH layers. Waves 0-3: L0 gates; waves 4-7: L1 gates.
// Epoch e (0..512): L0 computes step e (e<512) from h0buf=H0[e-1]; L1 computes step e-1
// (e>=1) from x=H0[e-1], carry H1[e-2]. xg1 = in-register matvec (wreg2).
// Sync (round-6-proven): relaxed agent-scope flags, 96 lines, one per block.
// Wave 0 performs BOTH layers' gate-combine and owns ALL global h-stores ->
// single inline s_waitcnt vmcnt(0) then one flag store (= e+2) at the tail.
// Poll at e>=1: t<96 wait flags >= e+1. Parity: read hx[e&1], write hx[(e+1)&1].
// Flags monotone; hx0/hx1/flags memset 0 before launch.

__global__ __launch_bounds__(512) void lstm_fused(
    const float* __restrict__ xg0,    // (2048,3072) layer-0 input projections
    const float* __restrict__ Wih1,   // (3072,768) fp32 layer-1 input weights
    const float* __restrict__ Whh,    // (2,3072,768) fp32
    const float* __restrict__ bias,   // (2,3072) fp32
    float* __restrict__ hx0,          // [2][3072] (k,b), pre-zeroed
    float* __restrict__ hx1,          // [2][3072] (k,b), pre-zeroed
    _Float16* __restrict__ h1hist,    // (2048,768) fp16, row = t*4+b
    unsigned* __restrict__ flags)     // [96*32], pre-zeroed
{
  __shared__ __align__(16) float h0buf[H_SZ * 4];   // [k][b]
  __shared__ __align__(16) float h1buf[H_SZ * 4];   // [k][b]
  __shared__ __align__(16) float redA[4][8][4][4];  // L0 [gate][c][q][b]
  __shared__ __align__(16) float redB[4][8][4][4];  // L1
  __shared__ float actvA[4][8][4], actvB[4][8][4];
  __shared__ float cst0[8][4], cst1[8][4];

  const int t = threadIdx.x, lane = t & 63, wv = t >> 6;
  const int j0 = blockIdx.x * 8;
  const bool isL1w = wv >= 4;
  const int g = isL1w ? (wv - 4) : wv;   // gate index within layer

  // W_hh slice in registers (layer per wave group)
  const float* WhhL = Whh + (isL1w ? (size_t)G4 * H_SZ : 0);
  float wreg[8][12];
#pragma unroll
  for (int c = 0; c < 8; ++c)
#pragma unroll
    for (int kk = 0; kk < 12; ++kk)
      wreg[c][kk] = WhhL[(size_t)(g * H_SZ + j0 + c) * H_SZ + kk * 64 + lane];

  // L1 waves also hold W_ih1 slice
  float wreg2[8][12];
  if (isL1w) {
#pragma unroll
    for (int c = 0; c < 8; ++c)
#pragma unroll
      for (int kk = 0; kk < 12; ++kk)
        wreg2[c][kk] = Wih1[(size_t)(g * H_SZ + j0 + c) * H_SZ + kk * 64 + lane];
  }

  float breg = 0.f;
  if (t >= 256 && t < 384) {
    int t2 = t - 256;
    breg = bias[G4 + (t2 >> 5) * H_SZ + j0 + ((t2 >> 2) & 7)];
  }

  if (t < 32) cst0[t >> 2][t & 3] = 0.f;
  else if (t < 64) cst1[(t - 32) >> 2][(t - 32) & 3] = 0.f;

  for (int e = 0; e <= 512; ++e) {
    // L0 xg prefetch (independent of h) before the poll
    float xgv = 0.f;
    if (t < 128 && e < 512)
      xgv = xg0[(size_t)((e << 2) + (t & 3)) * G4 + (t >> 5) * H_SZ + j0 + ((t >> 2) & 7)];

    if (e >= 1 && t < FUSE_WGS) {
      while (__hip_atomic_load(&flags[t * 32], __ATOMIC_RELAXED, __HIP_MEMORY_SCOPE_AGENT)
             < (unsigned)(e + 1))
        __builtin_amdgcn_s_sleep(1);
    }
    __syncthreads();

    // gather both h states (parity e&1) into LDS: 3 x 8B slots each per thread
    {
      const ull* s0 = (const ull*)(hx0 + ((e & 1) ? 3072 : 0));
      const ull* s1 = (const ull*)(hx1 + ((e & 1) ? 3072 : 0));
      ull* d0 = (ull*)h0buf;
      ull* d1 = (ull*)h1buf;
#pragma unroll
      for (int i = 0; i < 3; ++i)
        d0[t + i * 512] = __hip_atomic_load(&s0[t + i * 512], __ATOMIC_RELAXED, __HIP_MEMORY_SCOPE_AGENT);
#pragma unroll
      for (int i = 0; i < 3; ++i)
        d1[t + i * 512] = __hip_atomic_load(&s1[t + i * 512], __ATOMIC_RELAXED, __HIP_MEMORY_SCOPE_AGENT);
    }
    __syncthreads();

    // matvec + butterfly reduce (wave-uniform guards)
    const bool act = isL1w ? (e >= 1) : (e < 512);
    if (act) {
      float4 acc[8];
#pragma unroll
      for (int c = 0; c < 8; ++c) acc[c] = make_float4(0.f, 0.f, 0.f, 0.f);

      if (!isL1w) {
#pragma unroll
        for (int kk = 0; kk < 12; ++kk) {
          float4 h4 = *(const float4*)&h0buf[(kk * 64 + lane) * 4];
#pragma unroll
          for (int c = 0; c < 8; ++c) {
            float wf = wreg[c][kk];
            acc[c].x = fmaf(wf, h4.x, acc[c].x);
            acc[c].y = fmaf(wf, h4.y, acc[c].y);
            acc[c].z = fmaf(wf, h4.z, acc[c].z);
            acc[c].w = fmaf(wf, h4.w, acc[c].w);
          }
        }
      } else {
#pragma unroll
        for (int kk = 0; kk < 12; ++kk) {
          float4 x4 = *(const float4*)&h0buf[(kk * 64 + lane) * 4];  // x = H0[e-1]
          float4 h4 = *(const float4*)&h1buf[(kk * 64 + lane) * 4];  // carry H1[e-2]
#pragma unroll
          for (int c = 0; c < 8; ++c) {
            float wx = wreg2[c][kk], wh = wreg[c][kk];
            acc[c].x = fmaf(wx, x4.x, fmaf(wh, h4.x, acc[c].x));
            acc[c].y = fmaf(wx, x4.y, fmaf(wh, h4.y, acc[c].y));
            acc[c].z = fmaf(wx, x4.z, fmaf(wh, h4.z, acc[c].z));
            acc[c].w = fmaf(wx, x4.w, fmaf(wh, h4.w, acc[c].w));
          }
        }
      }

#pragma unroll
      for (int mask = 1; mask <= 8; mask <<= 1) {
#pragma unroll
        for (int c = 0; c < 8; ++c) {
          acc[c].x += __shfl_xor(acc[c].x, mask, 64);
          acc[c].y += __shfl_xor(acc[c].y, mask, 64);
          acc[c].z += __shfl_xor(acc[c].z, mask, 64);
          acc[c].w += __shfl_xor(acc[c].w, mask, 64);
        }
      }
      if ((lane & 15) == 0) {
        int q = lane >> 4;
        float (*red)[8][4][4] = isL1w ? redB : redA;
#pragma unroll
        for (int c = 0; c < 8; ++c) *(float4*)&red[g][c][q][0] = acc[c];
      }
    }
    __syncthreads();

    // activations
    if (t < 128 && e < 512) {
      int gg = t >> 5, c = (t >> 2) & 7, b = t & 3;
      float s = redA[gg][c][0][b] + redA[gg][c][1][b] + redA[gg][c][2][b] + redA[gg][c][3][b] + xgv;
      actvA[gg][c][b] = (gg == 2) ? tanhf(s) : (1.f / (1.f + expf(-s)));
    } else if (t >= 256 && t < 384 && e >= 1) {
      int t2 = t - 256;
      int gg = t2 >> 5, c = (t2 >> 2) & 7, b = t2 & 3;
      float s = redB[gg][c][0][b] + redB[gg][c][1][b] + redB[gg][c][2][b] + redB[gg][c][3][b] + breg;
      actvB[gg][c][b] = (gg == 2) ? tanhf(s) : (1.f / (1.f + expf(-s)));
    }
    __syncthreads();

    // combine + ALL global h stores in wave 0
    if (t < 32) {
      if (e < 512) {
        int c = t >> 2, b = t & 3;
        float iv = actvA[0][c][b], fv = actvA[1][c][b], gv = actvA[2][c][b], ov = actvA[3][c][b];
        float cn = fv * cst0[c][b] + iv * gv;
        cst0[c][b] = cn;
        float hn = ov * tanhf(cn);
        float* hnext = hx0 + (((e + 1) & 1) ? 3072 : 0);
        __hip_atomic_store(&hnext[(j0 + c) * 4 + b], hn,
                           __ATOMIC_RELAXED, __HIP_MEMORY_SCOPE_AGENT);
      }
    } else if (t < 64) {
      if (e >= 1) {
        int u = t - 32, c = u >> 2, b = u & 3;
        float iv = actvB[0][c][b], fv = actvB[1][c][b], gv = actvB[2][c][b], ov = actvB[3][c][b];
        float cn = fv * cst1[c][b] + iv * gv;
        cst1[c][b] = cn;
        float hn = ov * tanhf(cn);
        float* hnext = hx1 + (((e + 1) & 1) ? 3072 : 0);
        __hip_atomic_store(&hnext[(j0 + c) * 4 + b], hn,
                           __ATOMIC_RELAXED, __HIP_MEMORY_SCOPE_AGENT);
        h1hist[(size_t)(((e - 1) << 2) + b) * H_SZ + j0 + c] = (_Float16)hn;
      }
    }

    // tail publication: wave 0 owns all h-stores; drain then flag
    if (e < 512 && wv == 0) {
      asm volatile("s_waitcnt vmcnt(0)" ::: "memory");
      if (t == 0)
        __hip_atomic_store(&flags[blockIdx.x * 32], (unsigned)(e + 2),
                           __ATOMIC_RELAXED, __HIP_MEMORY_SCOPE_AGENT);
    }
    // top-of-epoch poll + __syncthreads separate this epoch's LDS/global
    // reads from next epoch's overwrites (see round-6 safety argument).
  }
}

// ---------------- launcher ----------------

extern "C" void kernel_launch(void* const* d_in, const int* in_sizes, int n_in,
                              void* d_out, int out_size, void* d_ws, size_t ws_size,
                              hipStream_t stream) {
  const float* reps   = (const float*)d_in[0];
  const float* W_ih   = (const float*)d_in[1];
  const float* W_hh   = (const float*)d_in[2];
  const float* bias   = (const float*)d_in[3];
  const float* head_w = (const float*)d_in[4];
  const float* head_b = (const float*)d_in[5];
  float* out = (float*)d_out;

  char* ws = (char*)d_ws;
  _Float16* A0h    = (_Float16*)(ws + 0);            //  3,145,728 B
  _Float16* Wih_h  = (_Float16*)(ws + 3145728);      //  4,718,592 B (layer 0 only)
  _Float16* Whead  = (_Float16*)(ws + 12582912);     // 77,266,944 B (padded)
  float*    xg0    = (float*)   (ws + 89849856);     // 25,165,824 B
  _Float16* h1hist = (_Float16*)(ws + 115015680);    //  3,145,728 B
  float*    hx0    = (float*)   (ws + 118161408);    //     24,576 B
  float*    hx1    = (float*)   (ws + 118185984);    //     24,576 B
  unsigned* flags  = (unsigned*)(ws + 118210560);    //     12,288 B (96*128B)

  // conversions
  hipLaunchKernelGGL(conv_A0,   dim3(1024), dim3(256), 0, stream, reps, A0h);
  hipLaunchKernelGGL(conv_cast, dim3(1024), dim3(256), 0, stream, W_ih, Wih_h, G4 * D_SZ);
  hipLaunchKernelGGL(conv_head, dim3(4096), dim3(256), 0, stream, head_w, Whead);

  // xg0 = A0 * Wih0^T + b0
  hipLaunchKernelGGL(gemm_bt_f16, dim3(16, 24), dim3(256), 0, stream,
                     A0h, Wih_h, bias, xg0, M_SZ, G4, H_SZ, 0, G4);

  // fused pipelined 2-layer scan (96 blocks x 512 threads, co-resident)
  hipMemsetAsync(hx0, 0, 61440, stream);  // hx0 + hx1 + flags contiguous
  hipLaunchKernelGGL(lstm_fused, dim3(FUSE_WGS), dim3(512), 0, stream,
                     xg0, W_ih + (size_t)G4 * D_SZ, W_hh, bias,
                     hx0, hx1, h1hist, flags);

  // logits = h1 * head_w^T + head_b  (padded N, permuted store into (B,T,V))
  hipLaunchKernelGGL(gemm_bt_f16, dim3(16, 393), dim3(256), 0, stream,
                     h1hist, Whead, head_b, out, M_SZ, V_PAD, H_SZ, 1, V_SZ);
}

// Round 9
// 12206.213 us; speedup vs baseline: 1.0041x; 1.0041x over previous
//
#include <hip/hip_runtime.h>
#include <hip/hip_fp16.h>
#include <cstdint>

#define B_SZ 4
#define T_SZ 512
#define D_SZ 768
#define H_SZ 768
#define G4   3072           // 4*H
#define V_SZ 50257
#define V_PAD 50304         // 393*128
#define M_SZ 2048           // T*B
#define FUSE_WGS 96         // one block = 8 cols of L0 (waves 0-3) + 8 cols of L1 (waves 4-7)

using half8 = __attribute__((ext_vector_type(8))) _Float16;
using f32x4 = __attribute__((ext_vector_type(4))) float;
typedef unsigned long long ull;

// ---------------- conversion kernels ----------------

__global__ void conv_A0(const float* __restrict__ reps, _Float16* __restrict__ A0) {
  // A0[(t*4+b)*768 + k] = reps[(b*512 + t)*768 + k]
  int idx = blockIdx.x * blockDim.x + threadIdx.x;
  const int total = M_SZ * D_SZ;
  for (; idx < total; idx += gridDim.x * blockDim.x) {
    int k = idx % D_SZ, m = idx / D_SZ;
    int t = m >> 2, b = m & 3;
    A0[idx] = (_Float16)reps[(b * T_SZ + t) * D_SZ + k];
  }
}

__global__ void conv_cast(const float* __restrict__ src, _Float16* __restrict__ dst, int n) {
  int idx = blockIdx.x * blockDim.x + threadIdx.x;
  for (; idx < n; idx += gridDim.x * blockDim.x) dst[idx] = (_Float16)src[idx];
}

__global__ void conv_head(const float* __restrict__ w, _Float16* __restrict__ dst) {
  int idx = blockIdx.x * blockDim.x + threadIdx.x;
  const int total = V_PAD * H_SZ;
  for (; idx < total; idx += gridDim.x * blockDim.x) {
    int n = idx / H_SZ, k = idx % H_SZ;
    dst[idx] = (n < V_SZ) ? (_Float16)w[n * H_SZ + k] : (_Float16)0.f;
  }
}

// ---------------- f16 MFMA GEMM: C[m][n] = sum_k A[m][k]*B[n][k] + bias[n] ----------------

__global__ __launch_bounds__(256) void gemm_bt_f16(
    const _Float16* __restrict__ A, const _Float16* __restrict__ B,
    const float* __restrict__ bias, float* __restrict__ C,
    int M, int N, int K, int mode, int Nreal)
{
  __shared__ __align__(16) _Float16 As[128][32];
  __shared__ __align__(16) _Float16 Bs[128][32];
  const int t = threadIdx.x;
  const int lane = t & 63, w = t >> 6;
  const int wr = w >> 1, wc = w & 1;
  const int m0 = blockIdx.x * 128, n0 = blockIdx.y * 128;

  f32x4 acc[4][4] = {};

  const int srow = t >> 2;
  const int scol = (t & 3) * 8;

  for (int k0 = 0; k0 < K; k0 += 32) {
    uint4 av0 = *(const uint4*)&A[(size_t)(m0 + srow) * K + k0 + scol];
    uint4 av1 = *(const uint4*)&A[(size_t)(m0 + 64 + srow) * K + k0 + scol];
    uint4 bv0 = *(const uint4*)&B[(size_t)(n0 + srow) * K + k0 + scol];
    uint4 bv1 = *(const uint4*)&B[(size_t)(n0 + 64 + srow) * K + k0 + scol];
    __syncthreads();
    *(uint4*)&As[srow][scol]      = av0;
    *(uint4*)&As[64 + srow][scol] = av1;
    *(uint4*)&Bs[srow][scol]      = bv0;
    *(uint4*)&Bs[64 + srow][scol] = bv1;
    __syncthreads();

    const int fr = lane & 15, k8 = (lane >> 4) * 8;
    half8 af[4], bf[4];
#pragma unroll
    for (int i = 0; i < 4; ++i) {
      af[i] = *(const half8*)&As[wr * 64 + i * 16 + fr][k8];
      bf[i] = *(const half8*)&Bs[wc * 64 + i * 16 + fr][k8];
    }
#pragma unroll
    for (int i = 0; i < 4; ++i)
#pragma unroll
      for (int j = 0; j < 4; ++j)
        acc[i][j] = __builtin_amdgcn_mfma_f32_16x16x32_f16(af[i], bf[j], acc[i][j], 0, 0, 0);
  }

  const int fr = lane & 15, rq = lane >> 4;
#pragma unroll
  for (int i = 0; i < 4; ++i) {
#pragma unroll
    for (int j = 0; j < 4; ++j) {
      int n = n0 + wc * 64 + j * 16 + fr;
      if (n >= Nreal) continue;
      float bv = bias[n];
#pragma unroll
      for (int r = 0; r < 4; ++r) {
        int m = m0 + wr * 64 + i * 16 + rq * 4 + r;
        float v = acc[i][j][r] + bv;
        if (mode == 0) {
          C[(size_t)m * N + n] = v;
        } else {
          int tt = m >> 2, bb = m & 3;
          C[(size_t)(bb * T_SZ + tt) * V_SZ + n] = v;
        }
      }
    }
  }
}

// ---------------- fused 2-layer pipelined LSTM scan: 96 blocks x 512 threads ----------------
// Block owns h-cols [j0, j0+8) of BOTH layers. Waves 0-3: L0 gates; waves 4-7: L1 gates.
// Epoch e (0..512): L0 computes step e (e<512) from h0buf=H0[e-1]; L1 computes step e-1
// (e>=1) from x=H0[e-1], carry H1[e-2]. xg1 = in-register matvec (wreg2).
// Sync (round-6-proven): relaxed agent-scope flags, 96 lines, one per block.
// Wave 0 performs BOTH layers' gate-combine and owns ALL global h-stores ->
// single inline s_waitcnt vmcnt(0) then one flag store (= e+2) at the tail.
// Poll at e>=1: t<96 wait flags >= e+1. Parity: read hx[e&1], write hx[(e+1)&1].
// Flags monotone; hx0/hx1/flags memset 0 before launch.
//
// __launch_bounds__(512, 2): 2 waves/EU = 1 block/CU -> 256-VGPR budget.
// Round 8 lesson: without the min-waves arg the compiler targeted 128 VGPR
// (2 blocks/CU) and SPILLED the ~192 weight registers -> 6 GB/launch scratch
// re-reads (FETCH_SIZE counter) and 23 us/epoch. Weights MUST stay resident.

__global__ __launch_bounds__(512, 2) void lstm_fused(
    const float* __restrict__ xg0,    // (2048,3072) layer-0 input projections
    const float* __restrict__ Wih1,   // (3072,768) fp32 layer-1 input weights
    const float* __restrict__ Whh,    // (2,3072,768) fp32
    const float* __restrict__ bias,   // (2,3072) fp32
    float* __restrict__ hx0,          // [2][3072] (k,b), pre-zeroed
    float* __restrict__ hx1,          // [2][3072] (k,b), pre-zeroed
    _Float16* __restrict__ h1hist,    // (2048,768) fp16, row = t*4+b
    unsigned* __restrict__ flags)     // [96*32], pre-zeroed
{
  __shared__ __align__(16) float h0buf[H_SZ * 4];   // [k][b]
  __shared__ __align__(16) float h1buf[H_SZ * 4];   // [k][b]
  __shared__ __align__(16) float redA[4][8][4][4];  // L0 [gate][c][q][b]
  __shared__ __align__(16) float redB[4][8][4][4];  // L1
  __shared__ float actvA[4][8][4], actvB[4][8][4];
  __shared__ float cst0[8][4], cst1[8][4];

  const int t = threadIdx.x, lane = t & 63, wv = t >> 6;
  const int j0 = blockIdx.x * 8;
  const bool isL1w = wv >= 4;
  const int g = isL1w ? (wv - 4) : wv;   // gate index within layer

  // W_hh slice in registers (layer per wave group)
  const float* WhhL = Whh + (isL1w ? (size_t)G4 * H_SZ : 0);
  float wreg[8][12];
#pragma unroll
  for (int c = 0; c < 8; ++c)
#pragma unroll
    for (int kk = 0; kk < 12; ++kk)
      wreg[c][kk] = WhhL[(size_t)(g * H_SZ + j0 + c) * H_SZ + kk * 64 + lane];

  // L1 waves also hold W_ih1 slice
  float wreg2[8][12];
  if (isL1w) {
#pragma unroll
    for (int c = 0; c < 8; ++c)
#pragma unroll
      for (int kk = 0; kk < 12; ++kk)
        wreg2[c][kk] = Wih1[(size_t)(g * H_SZ + j0 + c) * H_SZ + kk * 64 + lane];
  }

  float breg = 0.f;
  if (t >= 256 && t < 384) {
    int t2 = t - 256;
    breg = bias[G4 + (t2 >> 5) * H_SZ + j0 + ((t2 >> 2) & 7)];
  }

  if (t < 32) cst0[t >> 2][t & 3] = 0.f;
  else if (t < 64) cst1[(t - 32) >> 2][(t - 32) & 3] = 0.f;

  for (int e = 0; e <= 512; ++e) {
    // L0 xg prefetch (independent of h) before the poll
    float xgv = 0.f;
    if (t < 128 && e < 512)
      xgv = xg0[(size_t)((e << 2) + (t & 3)) * G4 + (t >> 5) * H_SZ + j0 + ((t >> 2) & 7)];

    if (e >= 1 && t < FUSE_WGS) {
      while (__hip_atomic_load(&flags[t * 32], __ATOMIC_RELAXED, __HIP_MEMORY_SCOPE_AGENT)
             < (unsigned)(e + 1))
        __builtin_amdgcn_s_sleep(1);
    }
    __syncthreads();

    // gather both h states (parity e&1) into LDS: 3 x 8B slots each per thread
    {
      const ull* s0 = (const ull*)(hx0 + ((e & 1) ? 3072 : 0));
      const ull* s1 = (const ull*)(hx1 + ((e & 1) ? 3072 : 0));
      ull* d0 = (ull*)h0buf;
      ull* d1 = (ull*)h1buf;
#pragma unroll
      for (int i = 0; i < 3; ++i)
        d0[t + i * 512] = __hip_atomic_load(&s0[t + i * 512], __ATOMIC_RELAXED, __HIP_MEMORY_SCOPE_AGENT);
#pragma unroll
      for (int i = 0; i < 3; ++i)
        d1[t + i * 512] = __hip_atomic_load(&s1[t + i * 512], __ATOMIC_RELAXED, __HIP_MEMORY_SCOPE_AGENT);
    }
    __syncthreads();

    // matvec + butterfly reduce (wave-uniform guards)
    const bool act = isL1w ? (e >= 1) : (e < 512);
    if (act) {
      float4 acc[8];
#pragma unroll
      for (int c = 0; c < 8; ++c) acc[c] = make_float4(0.f, 0.f, 0.f, 0.f);

      if (!isL1w) {
#pragma unroll
        for (int kk = 0; kk < 12; ++kk) {
          float4 h4 = *(const float4*)&h0buf[(kk * 64 + lane) * 4];
#pragma unroll
          for (int c = 0; c < 8; ++c) {
            float wf = wreg[c][kk];
            acc[c].x = fmaf(wf, h4.x, acc[c].x);
            acc[c].y = fmaf(wf, h4.y, acc[c].y);
            acc[c].z = fmaf(wf, h4.z, acc[c].z);
            acc[c].w = fmaf(wf, h4.w, acc[c].w);
          }
        }
      } else {
#pragma unroll
        for (int kk = 0; kk < 12; ++kk) {
          float4 x4 = *(const float4*)&h0buf[(kk * 64 + lane) * 4];  // x = H0[e-1]
          float4 h4 = *(const float4*)&h1buf[(kk * 64 + lane) * 4];  // carry H1[e-2]
#pragma unroll
          for (int c = 0; c < 8; ++c) {
            float wx = wreg2[c][kk], wh = wreg[c][kk];
            acc[c].x = fmaf(wx, x4.x, fmaf(wh, h4.x, acc[c].x));
            acc[c].y = fmaf(wx, x4.y, fmaf(wh, h4.y, acc[c].y));
            acc[c].z = fmaf(wx, x4.z, fmaf(wh, h4.z, acc[c].z));
            acc[c].w = fmaf(wx, x4.w, fmaf(wh, h4.w, acc[c].w));
          }
        }
      }

#pragma unroll
      for (int mask = 1; mask <= 8; mask <<= 1) {
#pragma unroll
        for (int c = 0; c < 8; ++c) {
          acc[c].x += __shfl_xor(acc[c].x, mask, 64);
          acc[c].y += __shfl_xor(acc[c].y, mask, 64);
          acc[c].z += __shfl_xor(acc[c].z, mask, 64);
          acc[c].w += __shfl_xor(acc[c].w, mask, 64);
        }
      }
      if ((lane & 15) == 0) {
        int q = lane >> 4;
        float (*red)[8][4][4] = isL1w ? redB : redA;
#pragma unroll
        for (int c = 0; c < 8; ++c) *(float4*)&red[g][c][q][0] = acc[c];
      }
    }
    __syncthreads();

    // activations
    if (t < 128 && e < 512) {
      int gg = t >> 5, c = (t >> 2) & 7, b = t & 3;
      float s = redA[gg][c][0][b] + redA[gg][c][1][b] + redA[gg][c][2][b] + redA[gg][c][3][b] + xgv;
      actvA[gg][c][b] = (gg == 2) ? tanhf(s) : (1.f / (1.f + expf(-s)));
    } else if (t >= 256 && t < 384 && e >= 1) {
      int t2 = t - 256;
      int gg = t2 >> 5, c = (t2 >> 2) & 7, b = t2 & 3;
      float s = redB[gg][c][0][b] + redB[gg][c][1][b] + redB[gg][c][2][b] + redB[gg][c][3][b] + breg;
      actvB[gg][c][b] = (gg == 2) ? tanhf(s) : (1.f / (1.f + expf(-s)));
    }
    __syncthreads();

    // combine + ALL global h stores in wave 0
    if (t < 32) {
      if (e < 512) {
        int c = t >> 2, b = t & 3;
        float iv = actvA[0][c][b], fv = actvA[1][c][b], gv = actvA[2][c][b], ov = actvA[3][c][b];
        float cn = fv * cst0[c][b] + iv * gv;
        cst0[c][b] = cn;
        float hn = ov * tanhf(cn);
        float* hnext = hx0 + (((e + 1) & 1) ? 3072 : 0);
        __hip_atomic_store(&hnext[(j0 + c) * 4 + b], hn,
                           __ATOMIC_RELAXED, __HIP_MEMORY_SCOPE_AGENT);
      }
    } else if (t < 64) {
      if (e >= 1) {
        int u = t - 32, c = u >> 2, b = u & 3;
        float iv = actvB[0][c][b], fv = actvB[1][c][b], gv = actvB[2][c][b], ov = actvB[3][c][b];
        float cn = fv * cst1[c][b] + iv * gv;
        cst1[c][b] = cn;
        float hn = ov * tanhf(cn);
        float* hnext = hx1 + (((e + 1) & 1) ? 3072 : 0);
        __hip_atomic_store(&hnext[(j0 + c) * 4 + b], hn,
                           __ATOMIC_RELAXED, __HIP_MEMORY_SCOPE_AGENT);
        h1hist[(size_t)(((e - 1) << 2) + b) * H_SZ + j0 + c] = (_Float16)hn;
      }
    }

    // tail publication: wave 0 owns all h-stores; drain then flag
    if (e < 512 && wv == 0) {
      asm volatile("s_waitcnt vmcnt(0)" ::: "memory");
      if (t == 0)
        __hip_atomic_store(&flags[blockIdx.x * 32], (unsigned)(e + 2),
                           __ATOMIC_RELAXED, __HIP_MEMORY_SCOPE_AGENT);
    }
    // top-of-epoch poll + __syncthreads separate this epoch's LDS/global
    // reads from next epoch's overwrites (see round-6 safety argument).
  }
}

// ---------------- launcher ----------------

extern "C" void kernel_launch(void* const* d_in, const int* in_sizes, int n_in,
                              void* d_out, int out_size, void* d_ws, size_t ws_size,
                              hipStream_t stream) {
  const float* reps   = (const float*)d_in[0];
  const float* W_ih   = (const float*)d_in[1];
  const float* W_hh   = (const float*)d_in[2];
  const float* bias   = (const float*)d_in[3];
  const float* head_w = (const float*)d_in[4];
  const float* head_b = (const float*)d_in[5];
  float* out = (float*)d_out;

  char* ws = (char*)d_ws;
  _Float16* A0h    = (_Float16*)(ws + 0);            //  3,145,728 B
  _Float16* Wih_h  = (_Float16*)(ws + 3145728);      //  4,718,592 B (layer 0 only)
  _Float16* Whead  = (_Float16*)(ws + 12582912);     // 77,266,944 B (padded)
  float*    xg0    = (float*)   (ws + 89849856);     // 25,165,824 B
  _Float16* h1hist = (_Float16*)(ws + 115015680);    //  3,145,728 B
  float*    hx0    = (float*)   (ws + 118161408);    //     24,576 B
  float*    hx1    = (float*)   (ws + 118185984);    //     24,576 B
  unsigned* flags  = (unsigned*)(ws + 118210560);    //     12,288 B (96*128B)

  // conversions
  hipLaunchKernelGGL(conv_A0,   dim3(1024), dim3(256), 0, stream, reps, A0h);
  hipLaunchKernelGGL(conv_cast, dim3(1024), dim3(256), 0, stream, W_ih, Wih_h, G4 * D_SZ);
  hipLaunchKernelGGL(conv_head, dim3(4096), dim3(256), 0, stream, head_w, Whead);

  // xg0 = A0 * Wih0^T + b0
  hipLaunchKernelGGL(gemm_bt_f16, dim3(16, 24), dim3(256), 0, stream,
                     A0h, Wih_h, bias, xg0, M_SZ, G4, H_SZ, 0, G4);

  // fused pipelined 2-layer scan (96 blocks x 512 threads, co-resident)
  hipMemsetAsync(hx0, 0, 61440, stream);  // hx0 + hx1 + flags contiguous
  hipLaunchKernelGGL(lstm_fused, dim3(FUSE_WGS), dim3(512), 0, stream,
                     xg0, W_ih + (size_t)G4 * D_SZ, W_hh, bias,
                     hx0, hx1, h1hist, flags);

  // logits = h1 * head_w^T + head_b  (padded N, permuted store into (B,T,V))
  hipLaunchKernelGGL(gemm_bt_f16, dim3(16, 393), dim3(256), 0, stream,
                     h1hist, Whead, head_b, out, M_SZ, V_PAD, H_SZ, 1, V_SZ);
}